// Round 8
// baseline (49.695 us; speedup 1.0000x reference)
//
#include <hip/hip_runtime.h>
#include <math.h>

#define PI_HALF 1.57079632679489662f

typedef float v2f __attribute__((ext_vector_type(2)));
typedef unsigned uv2 __attribute__((ext_vector_type(2)));

// ---------------------------------------------------------------------------
// R8: 2 samples / wave (8192 waves = 100% of the chip's wave slots),
// 32 lanes / sample, 8 complex amps / lane, with R5's packing discipline.
// Amplitude index i: bits [7:3] = g (lane&31) -> qubits 0..4
//                    bits [2:0] = (j1,j0,h)   -> qubits 5,6,7
// State: v2f RE[4], IM[4] (h packed in the v2f).
// Qubit w<=4 -> g bit (4-w): bit4=DPP row parity (row_mask), bit3/bit2=DPP
// bank bits (bank_mask), bits 1,0 = in-quad (quad_perm). xor16 crosses rows
// via permlane16_swap. Lane-control CNOTs = ONE masked DPP per scalar.
// MLPs: packed across the wave's two samples (weights are sample-uniform).
// ---------------------------------------------------------------------------

__device__ __forceinline__ v2f sp(float x) { v2f r; r.x = x; r.y = x; return r; }
__device__ __forceinline__ v2f pkfma(v2f a, v2f b, v2f c) {
  return __builtin_elementwise_fma(a, b, c);
}

template <int CTRL>
__device__ __forceinline__ float dpp_mov(float v) {
  int r = __builtin_amdgcn_update_dpp(0, __float_as_int(v), CTRL, 0xf, 0xf, true);
  return __int_as_float(r);
}
// Masked DPP: lanes outside ROW/BANK keep old value.
template <int CTRL, int ROW, int BANK>
__device__ __forceinline__ float mdpp(float old_, float src) {
  int r = __builtin_amdgcn_update_dpp(__float_as_int(old_), __float_as_int(src),
                                      CTRL, ROW, BANK, false);
  return __int_as_float(r);
}

__device__ __forceinline__ float xor16f(float v, bool odd) {
#if __has_builtin(__builtin_amdgcn_permlane16_swap)
  uv2 r = __builtin_amdgcn_permlane16_swap(__float_as_uint(v),
                                           __float_as_uint(v), false, false);
  return __uint_as_float(odd ? r.x : r.y);
#else
  return __int_as_float(__builtin_amdgcn_ds_swizzle(__float_as_int(v), 0x401F));
#endif
}

template <int MASK>  // xor of lane bits within 32-lane sample group
__device__ __forceinline__ float lane_xor(float v, bool odd) {
  if constexpr (MASK == 1) return dpp_mov<0xB1>(v);        // quad [1,0,3,2]
  else if constexpr (MASK == 2) return dpp_mov<0x4E>(v);   // quad [2,3,0,1]
  else if constexpr (MASK == 4) return dpp_mov<0x1B>(dpp_mov<0x141>(v));
  else if constexpr (MASK == 8) return dpp_mov<0x128>(v);  // row_ror:8
  else return xor16f(v, odd);
}
template <int MASK>
__device__ __forceinline__ v2f dpp2(v2f v, bool odd) {
  v2f r; r.x = lane_xor<MASK>(v.x, odd); r.y = lane_xor<MASK>(v.y, odd);
  return r;
}

// --- Rot gates. mA = (m00r,m00i,m01r,m01i); m11=conj(m00), m10=-conj(m01)
template <int W>  // lane qubit, W in 0..4
__device__ __forceinline__ void rot_lane(v2f (&RE)[4], v2f (&IM)[4],
                                         const float4 mA, int g) {
  constexpr int LM = 1 << (4 - W);
  const bool odd = (g >> 4) & 1;
  const unsigned bit = (g >> (4 - W)) & 1u;
  const int sgn = (int)(bit << 31);
  v2f Av = sp(mA.x);
  v2f Bv = sp(__int_as_float(__float_as_int(mA.y) ^ sgn));
  v2f Cv = sp(__int_as_float(__float_as_int(mA.z) ^ sgn));
  v2f Dv = sp(mA.w);
#pragma unroll
  for (int j = 0; j < 4; ++j) {
    v2f pr = dpp2<LM>(RE[j], odd);
    v2f pi = dpp2<LM>(IM[j], odd);
    v2f nr = pkfma(-Dv, pi, pkfma(Cv, pr, pkfma(-Bv, IM[j], Av * RE[j])));
    v2f ni = pkfma( Dv, pr, pkfma(Cv, pi, pkfma( Bv, RE[j], Av * IM[j])));
    RE[j] = nr; IM[j] = ni;
  }
}

template <int JM>  // reg qubit via j-bit: q5 JM=2, q6 JM=1
__device__ __forceinline__ void rot_regj(v2f (&RE)[4], v2f (&IM)[4],
                                         const float4 mA) {
  v2f M0r = sp(mA.x), M0i = sp(mA.y), M1r = sp(mA.z), M1i = sp(mA.w);
#pragma unroll
  for (int j = 0; j < 4; ++j) {
    if (!(j & JM)) {
      const int j1 = j | JM;
      v2f r0 = RE[j], i0 = IM[j], r1 = RE[j1], i1 = IM[j1];
      RE[j]  = pkfma(-M1i, i1, pkfma(M1r, r1, pkfma(-M0i, i0, M0r * r0)));
      IM[j]  = pkfma( M1i, r1, pkfma(M1r, i1, pkfma( M0i, r0, M0r * i0)));
      RE[j1] = pkfma( M0i, i1, pkfma(M0r, r1, pkfma(-M1i, i0, (-M1r) * r0)));
      IM[j1] = pkfma(-M0i, r1, pkfma(M0r, i1, pkfma( M1i, r0, (-M1r) * i0)));
    }
  }
}

__device__ __forceinline__ void rot_regh(v2f (&RE)[4], v2f (&IM)[4],
                                         const float4 mA) {  // q7 (h bit)
#pragma unroll
  for (int j = 0; j < 4; ++j) {
    float r0 = RE[j].x, i0 = IM[j].x, r1 = RE[j].y, i1 = IM[j].y;
    RE[j].x = fmaf(-mA.w, i1, fmaf(mA.z, r1, fmaf(-mA.y, i0, mA.x * r0)));
    IM[j].x = fmaf( mA.w, r1, fmaf(mA.z, i1, fmaf( mA.y, r0, mA.x * i0)));
    RE[j].y = fmaf( mA.y, i1, fmaf(mA.x, r1, fmaf(-mA.w, i0, -mA.z * r0)));
    IM[j].y = fmaf(-mA.y, r1, fmaf(mA.x, i1, fmaf( mA.w, r0, -mA.z * i0)));
  }
}

// --- CNOTs ---
// Lane control + lane target, single masked DPP per scalar.
template <int CTRL, int ROW, int BANK>
__device__ __forceinline__ void cnot_mask(v2f (&RE)[4], v2f (&IM)[4]) {
#pragma unroll
  for (int j = 0; j < 4; ++j) {
    RE[j].x = mdpp<CTRL, ROW, BANK>(RE[j].x, RE[j].x);
    RE[j].y = mdpp<CTRL, ROW, BANK>(RE[j].y, RE[j].y);
    IM[j].x = mdpp<CTRL, ROW, BANK>(IM[j].x, IM[j].x);
    IM[j].y = mdpp<CTRL, ROW, BANK>(IM[j].y, IM[j].y);
  }
}
// Lane control, target xor4 (needs xor7 then masked xor3).
template <int ROW, int BANK>
__device__ __forceinline__ void cnot_mask4(v2f (&RE)[4], v2f (&IM)[4]) {
#pragma unroll
  for (int j = 0; j < 4; ++j) {
    float t0 = dpp_mov<0x141>(RE[j].x);
    float t1 = dpp_mov<0x141>(RE[j].y);
    float t2 = dpp_mov<0x141>(IM[j].x);
    float t3 = dpp_mov<0x141>(IM[j].y);
    RE[j].x = mdpp<0x1B, ROW, BANK>(RE[j].x, t0);
    RE[j].y = mdpp<0x1B, ROW, BANK>(RE[j].y, t1);
    IM[j].x = mdpp<0x1B, ROW, BANK>(IM[j].x, t2);
    IM[j].y = mdpp<0x1B, ROW, BANK>(IM[j].y, t3);
  }
}
// Control g bit1, target xor1: pure quad_perm [0,1,3,2].
__device__ __forceinline__ void cnot_quadB4(v2f (&RE)[4], v2f (&IM)[4]) {
#pragma unroll
  for (int j = 0; j < 4; ++j) {
    RE[j].x = dpp_mov<0xB4>(RE[j].x);
    RE[j].y = dpp_mov<0xB4>(RE[j].y);
    IM[j].x = dpp_mov<0xB4>(IM[j].x);
    IM[j].y = dpp_mov<0xB4>(IM[j].y);
  }
}
// Control g bit GPOS (lane), target xor16.
template <int GPOS>
__device__ __forceinline__ void cnot_LL16(v2f (&RE)[4], v2f (&IM)[4], int g) {
  const bool cb = (g >> GPOS) & 1;
  const bool odd = (g >> 4) & 1;
#pragma unroll
  for (int j = 0; j < 4; ++j) {
    float a = xor16f(RE[j].x, odd), b = xor16f(RE[j].y, odd);
    float c = xor16f(IM[j].x, odd), d = xor16f(IM[j].y, odd);
    RE[j].x = cb ? a : RE[j].x;  RE[j].y = cb ? b : RE[j].y;
    IM[j].x = cb ? c : IM[j].x;  IM[j].y = cb ? d : IM[j].y;
  }
}
template <int GPOS, int JM>  // C lane, T reg j-bit
__device__ __forceinline__ void cnot_LR(v2f (&RE)[4], v2f (&IM)[4], int g) {
  const bool cb = (g >> GPOS) & 1;
#pragma unroll
  for (int j = 0; j < 4; ++j) {
    if (!(j & JM)) {
      const int j1 = j | JM;
      v2f r0 = RE[j], r1 = RE[j1];
      RE[j] = cb ? r1 : r0;  RE[j1] = cb ? r0 : r1;
      v2f i0 = IM[j], i1 = IM[j1];
      IM[j] = cb ? i1 : i0;  IM[j1] = cb ? i0 : i1;
    }
  }
}
template <int GPOS>  // C lane, T h
__device__ __forceinline__ void cnot_LH(v2f (&RE)[4], v2f (&IM)[4], int g) {
  const bool cb = (g >> GPOS) & 1;
#pragma unroll
  for (int j = 0; j < 4; ++j) {
    float rx = RE[j].x, ix = IM[j].x;
    RE[j].x = cb ? RE[j].y : rx;  RE[j].y = cb ? rx : RE[j].y;
    IM[j].x = cb ? IM[j].y : ix;  IM[j].y = cb ? ix : IM[j].y;
  }
}
template <int JSEL, int LM>  // C reg j-bit, T lane (DPP masks 1..8)
__device__ __forceinline__ void cnot_RL(v2f (&RE)[4], v2f (&IM)[4], int g) {
  const bool odd = (g >> 4) & 1;
#pragma unroll
  for (int j = 0; j < 4; ++j) {
    if (j & JSEL) {
      RE[j] = dpp2<LM>(RE[j], odd);
      IM[j] = dpp2<LM>(IM[j], odd);
    }
  }
}
template <int JSEL>  // C reg j-bit, T lane xor16
__device__ __forceinline__ void cnot_RL16(v2f (&RE)[4], v2f (&IM)[4], int g) {
  const bool odd = (g >> 4) & 1;
#pragma unroll
  for (int j = 0; j < 4; ++j) {
    if (j & JSEL) {
      RE[j].x = xor16f(RE[j].x, odd);  RE[j].y = xor16f(RE[j].y, odd);
      IM[j].x = xor16f(IM[j].x, odd);  IM[j].y = xor16f(IM[j].y, odd);
    }
  }
}
template <int JSEL>  // C reg j-bit, T h
__device__ __forceinline__ void cnot_RH(v2f (&RE)[4], v2f (&IM)[4]) {
#pragma unroll
  for (int j = 0; j < 4; ++j) {
    if (j & JSEL) {
      float t = RE[j].x; RE[j].x = RE[j].y; RE[j].y = t;
      t = IM[j].x; IM[j].x = IM[j].y; IM[j].y = t;
    }
  }
}
template <int LM>  // C h, T lane (only .y moves)
__device__ __forceinline__ void cnot_HL(v2f (&RE)[4], v2f (&IM)[4], int g) {
  const bool odd = (g >> 4) & 1;
#pragma unroll
  for (int j = 0; j < 4; ++j) {
    RE[j].y = lane_xor<LM>(RE[j].y, odd);
    IM[j].y = lane_xor<LM>(IM[j].y, odd);
  }
}
__device__ __forceinline__ void cnot_HL16(v2f (&RE)[4], v2f (&IM)[4], int g) {
  const bool odd = (g >> 4) & 1;
#pragma unroll
  for (int j = 0; j < 4; ++j) {
    RE[j].y = xor16f(RE[j].y, odd);
    IM[j].y = xor16f(IM[j].y, odd);
  }
}
template <int JC, int JT>  // C reg, T reg: static swaps
__device__ __forceinline__ void cnot_RR(v2f (&RE)[4], v2f (&IM)[4]) {
#pragma unroll
  for (int j = 0; j < 4; ++j) {
    if ((j & JC) && !(j & JT)) {
      const int j1 = j | JT;
      v2f t = RE[j]; RE[j] = RE[j1]; RE[j1] = t;
      t = IM[j]; IM[j] = IM[j1]; IM[j1] = t;
    }
  }
}

__device__ __forceinline__ void stage_fence() { __threadfence_block(); }

__global__ __launch_bounds__(256) void hqc_kernel(
    const float* __restrict__ x,
    const float* __restrict__ w1, const float* __restrict__ b1,
    const float* __restrict__ w2, const float* __restrict__ b2,
    const float* __restrict__ w3, const float* __restrict__ b3,
    const float* __restrict__ qw,
    const float* __restrict__ wp1, const float* __restrict__ bp1,
    const float* __restrict__ wp2, const float* __restrict__ bp2,
    const float* __restrict__ wp3, const float* __restrict__ bp3,
    float* __restrict__ out, int B) {
  __shared__ __align__(16) float rotm[32][4];
  __shared__ __align__(8) float xp[4][41][2];    // (sampleA, sampleB) pairs
  __shared__ __align__(8) float hp[4][64][2];
  __shared__ __align__(8) float h2p[4][32][2];
  __shared__ __align__(8) float qb[4][16][2];    // cos[8], sin[8] per half
  __shared__ __align__(8) float p1p[4][32][2];
  __shared__ __align__(8) float p2p[4][16][2];

  const int tid = threadIdx.x;
  const int lane = tid & 63;
  const int wv = tid >> 6;        // wave in block (0..3)
  const int half = (tid >> 5) & 1; // sample within wave
  const int g = tid & 31;          // lane within 32-lane sample group
  const int s = blockIdx.x * 8 + (tid >> 5);
  const bool valid = (s < B);

  // --- Rot coefficients: one thread per gate ---
  if (tid < 32) {
    float phi = qw[tid * 3 + 0];
    float th  = qw[tid * 3 + 1];
    float om  = qw[tid * 3 + 2];
    float st_, ct; sincosf(0.5f * th, &st_, &ct);
    float sa, ca;  sincosf(0.5f * (phi + om), &sa, &ca);
    float sb, cb;  sincosf(0.5f * (phi - om), &sb, &cb);
    rotm[tid][0] =  ca * ct;   // m00r
    rotm[tid][1] = -sa * ct;   // m00i
    rotm[tid][2] = -cb * st_;  // m01r
    rotm[tid][3] = -sb * st_;  // m01i
  }

  // --- stage x as (A,B) pairs ---
  if (valid) {
    xp[wv][g][half] = x[s * 41 + g];
    if (g < 9) xp[wv][g + 32][half] = x[s * 41 + 32 + g];
  }
  __syncthreads();

  // --- pre layer1: 41 -> 64. col = lane (64 cols), packed over samples ---
  {
    const int col = lane;
    v2f acc = sp(b1[col]);
#pragma unroll 8
    for (int k = 0; k < 41; ++k) {
      v2f xk = *(const v2f*)&xp[wv][k][0];
      acc = pkfma(xk, sp(w1[k * 64 + col]), acc);
    }
    acc.x = fmaxf(acc.x, 0.f); acc.y = fmaxf(acc.y, 0.f);
    *(v2f*)&hp[wv][col][0] = acc;
  }
  stage_fence();

  // --- layer2: 64 -> 32. col = g (halves duplicate), packed ---
  {
    v2f acc = sp(b2[g]);
#pragma unroll 8
    for (int k = 0; k < 64; ++k) {
      v2f hk = *(const v2f*)&hp[wv][k][0];
      acc = pkfma(hk, sp(w2[k * 32 + g]), acc);
    }
    acc.x = fmaxf(acc.x, 0.f); acc.y = fmaxf(acc.y, 0.f);
    if (half == 0) *(v2f*)&h2p[wv][g][0] = acc;
  }
  stage_fence();

  // --- layer3: 32 -> 8, tanh, RY. scalar, sample = half ---
  if (g < 8) {
    float acc = b3[g];
#pragma unroll
    for (int k = 0; k < 32; ++k)
      acc = fmaf(h2p[wv][k][half], w3[k * 8 + g], acc);
    float q = tanhf(acc);
    float sh, ch; sincosf(q * PI_HALF, &sh, &ch);
    qb[wv][g][half]     = ch;
    qb[wv][8 + g][half] = sh;
  }
  stage_fence();

  // --- init statevector ---
  float cwv[8], swv[8];
#pragma unroll
  for (int w = 0; w < 8; ++w) {
    cwv[w] = qb[wv][w][half];
    swv[w] = qb[wv][8 + w][half];
  }
  float lp = 1.0f;
#pragma unroll
  for (int w = 0; w < 5; ++w) lp *= ((g >> (4 - w)) & 1) ? swv[w] : cwv[w];
  float f56[4];
#pragma unroll
  for (int a = 0; a < 4; ++a)
    f56[a] = ((a & 2) ? swv[5] : cwv[5]) * ((a & 1) ? swv[6] : cwv[6]);
  v2f F7; F7.x = cwv[7]; F7.y = swv[7];
  v2f RE[4], IM[4];
#pragma unroll
  for (int j = 0; j < 4; ++j) {
    RE[j] = sp(lp * f56[j]) * F7;
    IM[j] = sp(0.0f);
  }

#define RM(L, W) (*(const float4*)(&rotm[(L) * 8 + (W)][0]))
#define ROTS(L)                                                          \
  {                                                                      \
    float4 c0 = RM(L, 0), c1 = RM(L, 1), c2 = RM(L, 2), c3 = RM(L, 3),   \
           c4 = RM(L, 4), c5 = RM(L, 5), c6 = RM(L, 6), c7 = RM(L, 7);   \
    rot_lane<0>(RE, IM, c0, g);                                          \
    rot_lane<1>(RE, IM, c1, g);                                          \
    rot_lane<2>(RE, IM, c2, g);                                          \
    rot_lane<3>(RE, IM, c3, g);                                          \
    rot_lane<4>(RE, IM, c4, g);                                          \
    rot_regj<2>(RE, IM, c5);                                             \
    rot_regj<1>(RE, IM, c6);                                             \
    rot_regh(RE, IM, c7);                                                \
  }

  // layer 0, r=1: (0,1)(1,2)(2,3)(3,4)(4,5)(5,6)(6,7)(7,0)
  ROTS(0)
  cnot_mask<0x128, 0xA, 0xF>(RE, IM);   // (0,1): ctrl row, xor8
  cnot_mask4<0xF, 0xC>(RE, IM);         // (1,2): ctrl bank{2,3}, xor4
  cnot_mask<0x4E, 0xF, 0xA>(RE, IM);    // (2,3): ctrl bank{1,3}, xor2
  cnot_quadB4(RE, IM);                  // (3,4): quad_perm [0,1,3,2]
  cnot_LR<0, 2>(RE, IM, g);             // (4,5)
  cnot_RR<2, 1>(RE, IM);                // (5,6)
  cnot_RH<1>(RE, IM);                   // (6,7)
  cnot_HL16(RE, IM, g);                 // (7,0)
  // layer 1, r=2: (0,2)(1,3)(2,4)(3,5)(4,6)(5,7)(6,0)(7,1)
  ROTS(1)
  cnot_mask4<0xA, 0xF>(RE, IM);         // (0,2)
  cnot_mask<0x4E, 0xF, 0xC>(RE, IM);    // (1,3)
  cnot_mask<0xB1, 0xF, 0xA>(RE, IM);    // (2,4)
  cnot_LR<1, 2>(RE, IM, g);             // (3,5)
  cnot_LR<0, 1>(RE, IM, g);             // (4,6)
  cnot_RH<2>(RE, IM);                   // (5,7)
  cnot_RL16<1>(RE, IM, g);              // (6,0)
  cnot_HL<8>(RE, IM, g);                // (7,1)
  // layer 2, r=3: (0,3)(1,4)(2,5)(3,6)(4,7)(5,0)(6,1)(7,2)
  ROTS(2)
  cnot_mask<0x4E, 0xA, 0xF>(RE, IM);    // (0,3)
  cnot_mask<0xB1, 0xF, 0xC>(RE, IM);    // (1,4)
  cnot_LR<2, 2>(RE, IM, g);             // (2,5)
  cnot_LR<1, 1>(RE, IM, g);             // (3,6)
  cnot_LH<0>(RE, IM, g);                // (4,7)
  cnot_RL16<2>(RE, IM, g);              // (5,0)
  cnot_RL<1, 8>(RE, IM, g);             // (6,1)
  cnot_HL<4>(RE, IM, g);                // (7,2)
  // layer 3, r=4: (0,4)(1,5)(2,6)(3,7)(4,0)(5,1)(6,2)(7,3)
  ROTS(3)
  cnot_mask<0xB1, 0xA, 0xF>(RE, IM);    // (0,4)
  cnot_LR<3, 2>(RE, IM, g);             // (1,5)
  cnot_LR<2, 1>(RE, IM, g);             // (2,6)
  cnot_LH<1>(RE, IM, g);                // (3,7)
  cnot_LL16<0>(RE, IM, g);              // (4,0)
  cnot_RL<2, 8>(RE, IM, g);             // (5,1)
  cnot_RL<1, 4>(RE, IM, g);             // (6,2)
  cnot_HL<2>(RE, IM, g);                // (7,3)

  // --- expectations ---
  v2f pv[4];
#pragma unroll
  for (int j = 0; j < 4; ++j) pv[j] = pkfma(RE[j], RE[j], IM[j] * IM[j]);
  v2f tv = (pv[0] + pv[1]) + (pv[2] + pv[3]);
  float tot = tv.x + tv.y;
  v2f v5 = pv[2] + pv[3]; float s5 = v5.x + v5.y;  // q5: j bit1
  v2f v6 = pv[1] + pv[3]; float s6 = v6.x + v6.y;  // q6: j bit0
  float s7 = tv.y;                                  // q7: h
  float zp[8];
  zp[0] = ((g >> 4) & 1) ? -tot : tot;
  zp[1] = ((g >> 3) & 1) ? -tot : tot;
  zp[2] = ((g >> 2) & 1) ? -tot : tot;
  zp[3] = ((g >> 1) & 1) ? -tot : tot;
  zp[4] = (g & 1) ? -tot : tot;
  zp[5] = fmaf(-2.f, s5, tot);
  zp[6] = fmaf(-2.f, s6, tot);
  zp[7] = fmaf(-2.f, s7, tot);
  {
    const bool odd = (g >> 4) & 1;
#pragma unroll
    for (int w = 0; w < 8; ++w) zp[w] += lane_xor<1>(zp[w], odd);
#pragma unroll
    for (int w = 0; w < 8; ++w) zp[w] += lane_xor<2>(zp[w], odd);
#pragma unroll
    for (int w = 0; w < 8; ++w) zp[w] += lane_xor<4>(zp[w], odd);
#pragma unroll
    for (int w = 0; w < 8; ++w) zp[w] += lane_xor<8>(zp[w], odd);
#pragma unroll
    for (int w = 0; w < 8; ++w) zp[w] += lane_xor<16>(zp[w], odd);
  }

  // --- post layer1: 8 -> 32. scalar, sample = half, col = g ---
  {
    float q1 = bp1[g];
#pragma unroll
    for (int k = 0; k < 8; ++k) q1 = fmaf(zp[k], wp1[k * 32 + g], q1);
    p1p[wv][g][half] = fmaxf(q1, 0.f);
  }
  stage_fence();

  // --- post layer2: 32 -> 16 ---
  if (g < 16) {
    float q2 = bp2[g];
#pragma unroll
    for (int k = 0; k < 32; ++k)
      q2 = fmaf(p1p[wv][k][half], wp2[k * 16 + g], q2);
    p2p[wv][g][half] = fmaxf(q2, 0.f);
  }
  stage_fence();

  // --- post layer3: 16 -> 5 ---
  if (g < 5 && valid) {
    float o = bp3[g];
#pragma unroll
    for (int k = 0; k < 16; ++k)
      o = fmaf(p2p[wv][k][half], wp3[k * 5 + g], o);
    out[s * 5 + g] = o;
  }
}

extern "C" void kernel_launch(void* const* d_in, const int* in_sizes, int n_in,
                              void* d_out, int out_size, void* d_ws,
                              size_t ws_size, hipStream_t stream) {
  const float* x   = (const float*)d_in[0];
  const float* w1  = (const float*)d_in[1];
  const float* b1  = (const float*)d_in[2];
  const float* w2  = (const float*)d_in[3];
  const float* b2  = (const float*)d_in[4];
  const float* w3  = (const float*)d_in[5];
  const float* b3  = (const float*)d_in[6];
  const float* qw  = (const float*)d_in[7];
  const float* wp1 = (const float*)d_in[8];
  const float* bp1 = (const float*)d_in[9];
  const float* wp2 = (const float*)d_in[10];
  const float* bp2 = (const float*)d_in[11];
  const float* wp3 = (const float*)d_in[12];
  const float* bp3 = (const float*)d_in[13];
  float* out = (float*)d_out;
  const int B = in_sizes[0] / 41;
  const int blocks = (B + 7) / 8;
  hipLaunchKernelGGL(hqc_kernel, dim3(blocks), dim3(256), 0, stream,
                     x, w1, b1, w2, b2, w3, b3, qw,
                     wp1, bp1, wp2, bp2, wp3, bp3, out, B);
}